// Round 1
// baseline (1363.057 us; speedup 1.0000x reference)
//
#include <hip/hip_runtime.h>

#define NN 50000          // nodes
#define NE 800000         // edges (without self loops)
#define NT (NE + NN)      // edges + self loops

// ---------------- graph preprocessing ----------------

__global__ void zero_deg_kernel(int* deg) {
  int v = blockIdx.x * 256 + threadIdx.x;
  if (v < NN) deg[v] = 0;
}

__global__ void count_deg_kernel(const int* __restrict__ edst, int* __restrict__ deg) {
  int i = blockIdx.x * 256 + threadIdx.x;
  if (i < NE) atomicAdd(&deg[edst[i]], 1);
}

__global__ void dinv_kernel(const int* __restrict__ deg, float* __restrict__ dinv) {
  int v = blockIdx.x * 256 + threadIdx.x;
  if (v < NN) dinv[v] = rsqrtf((float)(deg[v] + 1));   // +1 self loop
}

// inclusive scan of counts (deg+1) in chunks of 1024
__global__ __launch_bounds__(1024) void scan1_kernel(const int* __restrict__ deg,
                                                     int* __restrict__ incl,
                                                     int* __restrict__ bsum) {
  __shared__ int sd[1024];
  int gid = blockIdx.x * 1024 + threadIdx.x;
  int v = (gid < NN) ? (deg[gid] + 1) : 0;
  sd[threadIdx.x] = v;
  __syncthreads();
  for (int off = 1; off < 1024; off <<= 1) {
    int t = (threadIdx.x >= off) ? sd[threadIdx.x - off] : 0;
    __syncthreads();
    sd[threadIdx.x] += t;
    __syncthreads();
  }
  if (gid < NN) incl[gid] = sd[threadIdx.x];
  if (threadIdx.x == 1023) bsum[blockIdx.x] = sd[1023];
}

__global__ void scan2_kernel(int* bsum, int nb) {
  if (threadIdx.x == 0 && blockIdx.x == 0) {
    int run = 0;
    for (int i = 0; i < nb; ++i) { int t = bsum[i]; bsum[i] = run; run += t; }
  }
}

__global__ void scan3_kernel(const int* __restrict__ deg, const int* __restrict__ incl,
                             const int* __restrict__ bsum, int* __restrict__ offs,
                             int* __restrict__ cursor) {
  int v = blockIdx.x * 256 + threadIdx.x;
  if (v >= NN) return;
  int o = bsum[v >> 10] + incl[v] - (deg[v] + 1);
  offs[v] = o;
  cursor[v] = o;
  if (v == 0) offs[NN] = NT;
}

__global__ void fill_kernel(const int* __restrict__ esrc, const int* __restrict__ edst,
                            const float* __restrict__ dinv, int* __restrict__ cursor,
                            int* __restrict__ csrc, float* __restrict__ cw) {
  int i = blockIdx.x * 256 + threadIdx.x;
  if (i >= NT) return;
  int s, d;
  if (i < NE) { s = esrc[i]; d = edst[i]; }
  else        { s = d = i - NE; }           // self loop
  int p = atomicAdd(&cursor[d], 1);
  csrc[p] = s;
  cw[p] = dinv[s] * dinv[d];
}

// ---------------- dense GEMM: out = A[M,K] @ W[K,COLS] + bias ----------------
// block = 256 threads = 16(row-groups) x 16(col-groups); tile 64 rows x COLS.
// thread computes 4 rows x (COLS/16) cols.

template <int K, int COLS>
__global__ __launch_bounds__(256) void gemm_bias_kernel(const float* __restrict__ A,
                                                        const float* __restrict__ W,
                                                        const float* __restrict__ bias,
                                                        float* __restrict__ out, int M) {
  constexpr int CPT = COLS / 16;  // cols per thread (8 or 4)
  __shared__ float xs[64][65];    // +1 pad: kills 4-way bank conflict on row reads
  __shared__ float ws[64][COLS];  // unpadded: float4-aligned rows

  int tr = threadIdx.x / 16;      // 0..15 row group
  int tc = threadIdx.x % 16;      // 0..15 col group
  int row0 = blockIdx.x * 64;

  float acc[4][CPT] = {};

  for (int kc = 0; kc < K; kc += 64) {
    for (int i = threadIdx.x; i < 64 * 64; i += 256) {
      int r = i >> 6, k = i & 63;
      int row = row0 + r;
      xs[r][k] = (row < M) ? A[(size_t)row * K + kc + k] : 0.f;
    }
    for (int i = threadIdx.x; i < 64 * COLS; i += 256) {
      int k = i / COLS, c = i % COLS;
      ws[k][c] = W[(size_t)(kc + k) * COLS + c];
    }
    __syncthreads();
#pragma unroll 8
    for (int k = 0; k < 64; ++k) {
      float xv[4];
#pragma unroll
      for (int r = 0; r < 4; ++r) xv[r] = xs[tr * 4 + r][k];
      const float4* wrow = reinterpret_cast<const float4*>(&ws[k][tc * CPT]);
#pragma unroll
      for (int j4 = 0; j4 < CPT / 4; ++j4) {
        float4 wv = wrow[j4];
#pragma unroll
        for (int r = 0; r < 4; ++r) {
          acc[r][j4 * 4 + 0] += xv[r] * wv.x;
          acc[r][j4 * 4 + 1] += xv[r] * wv.y;
          acc[r][j4 * 4 + 2] += xv[r] * wv.z;
          acc[r][j4 * 4 + 3] += xv[r] * wv.w;
        }
      }
    }
    __syncthreads();
  }

#pragma unroll
  for (int r = 0; r < 4; ++r) {
    int row = row0 + tr * 4 + r;
    if (row < M) {
#pragma unroll
      for (int j = 0; j < CPT; ++j) {
        int c = tc * CPT + j;
        out[(size_t)row * COLS + c] = acc[r][j] + bias[c];
      }
    }
  }
}

// ---------------- propagation: out[d] = (sum_e w_e * h[src_e])  [* 0.9 + 0.1 h0] ----
// F threads per node (coalesced 4B/lane row gathers), 256/F nodes per block.

template <int F, bool APPNP>
__global__ __launch_bounds__(256) void prop_kernel(const float* __restrict__ hin,
                                                   const float* __restrict__ h0,
                                                   float* __restrict__ out,
                                                   const int* __restrict__ offs,
                                                   const int* __restrict__ csrc,
                                                   const float* __restrict__ cw) {
  constexpr int NPB = 256 / F;
  int node = blockIdx.x * NPB + threadIdx.x / F;
  int f = threadIdx.x % F;
  if (node >= NN) return;
  int e = offs[node];
  int e1 = offs[node + 1];
  float acc = 0.f;
  for (; e + 1 < e1; e += 2) {
    int s0 = csrc[e], s1 = csrc[e + 1];
    float w0 = cw[e], w1 = cw[e + 1];
    float v0 = hin[(size_t)s0 * F + f];
    float v1 = hin[(size_t)s1 * F + f];
    acc += w0 * v0;
    acc += w1 * v1;
  }
  if (e < e1) acc += cw[e] * hin[(size_t)csrc[e] * F + f];
  if (APPNP) acc = 0.9f * acc + 0.1f * h0[(size_t)node * F + f];
  out[(size_t)node * F + f] = acc;
}

// ---------------- launch ----------------

extern "C" void kernel_launch(void* const* d_in, const int* in_sizes, int n_in,
                              void* d_out, int out_size, void* d_ws, size_t ws_size,
                              hipStream_t stream) {
  const float* x    = (const float*)d_in[0];   // [50000,256]
  const int*   eidx = (const int*)d_in[1];     // [2,800000]
  const float* W1   = (const float*)d_in[2];   // [256,128]
  const float* b1   = (const float*)d_in[3];   // [128]
  const float* W3   = (const float*)d_in[4];   // [128,64]
  const float* b3   = (const float*)d_in[5];   // [64]
  float* outp = (float*)d_out;                 // [50000,64]

  const int* esrc = eidx;
  const int* edst = eidx + NE;

  // workspace layout (256B aligned)
  char* w = (char*)d_ws;
  size_t off = 0;
  auto take = [&](size_t bytes) {
    void* p = w + off;
    off = (off + bytes + 255) & ~(size_t)255;
    return p;
  };
  int*   deg    = (int*)take(NN * 4);
  float* dinv   = (float*)take(NN * 4);
  int*   incl   = (int*)take(NN * 4);
  int*   offs   = (int*)take((NN + 1) * 4);
  int*   cursor = (int*)take(NN * 4);
  int*   bsum   = (int*)take(64 * 4);
  int*   csrc   = (int*)take((size_t)NT * 4);
  float* cwv    = (float*)take((size_t)NT * 4);
  float* h0b    = (float*)take((size_t)NN * 128 * 4);
  float* ping   = (float*)take((size_t)NN * 128 * 4);
  float* pong   = (float*)take((size_t)NN * 128 * 4);
  (void)ws_size; (void)in_sizes; (void)n_in; (void)out_size;

  const int nblkN = (NN + 255) / 256;          // 196
  const int nblkE = (NE + 255) / 256;          // 3125
  const int nblkT = (NT + 255) / 256;          // 3321
  const int nbScan = (NN + 1023) / 1024;       // 49

  // --- graph norm + CSR build ---
  zero_deg_kernel<<<nblkN, 256, 0, stream>>>(deg);
  count_deg_kernel<<<nblkE, 256, 0, stream>>>(edst, deg);
  dinv_kernel<<<nblkN, 256, 0, stream>>>(deg, dinv);
  scan1_kernel<<<nbScan, 1024, 0, stream>>>(deg, incl, bsum);
  scan2_kernel<<<1, 64, 0, stream>>>(bsum, nbScan);
  scan3_kernel<<<nblkN, 256, 0, stream>>>(deg, incl, bsum, offs, cursor);
  fill_kernel<<<nblkT, 256, 0, stream>>>(esrc, edst, dinv, cursor, csrc, cwv);

  // --- GCNConv1: h0 = prop(x @ W1 + b1) ---
  const int gblk = (NN + 63) / 64;             // 782
  gemm_bias_kernel<256, 128><<<gblk, 256, 0, stream>>>(x, W1, b1, ping, NN);
  prop_kernel<128, false><<<NN / 2, 256, 0, stream>>>(ping, nullptr, h0b, offs, csrc, cwv);

  // --- APPNP: 10 x h = 0.9*prop(h) + 0.1*h0 ---
  const float* hc = h0b;
  float* bufs[2] = {ping, pong};
  for (int it = 0; it < 10; ++it) {
    float* hn = bufs[it & 1];
    prop_kernel<128, true><<<NN / 2, 256, 0, stream>>>(hc, h0b, hn, offs, csrc, cwv);
    hc = hn;
  }
  // hc == pong after 10 iters; ping is free
  float* t64 = ping;

  // --- GCNConv2: out = prop(h @ W3 + b3) ---
  gemm_bias_kernel<128, 64><<<gblk, 256, 0, stream>>>(hc, W3, b3, t64, NN);
  prop_kernel<64, false><<<(NN + 3) / 4, 256, 0, stream>>>(t64, nullptr, outp, offs, csrc, cwv);
}

// Round 2
// 915.461 us; speedup vs baseline: 1.4889x; 1.4889x over previous
//
#include <hip/hip_runtime.h>

#define NN 50000          // nodes
#define NE 800000         // edges (without self loops)
#define NT (NE + NN)      // edges + self loops

// ---------------- graph preprocessing ----------------

__global__ void zero_deg_kernel(int* deg) {
  int v = blockIdx.x * 256 + threadIdx.x;
  if (v < NN) deg[v] = 0;
}

__global__ void count_deg_kernel(const int* __restrict__ edst, int* __restrict__ deg) {
  int i = blockIdx.x * 256 + threadIdx.x;
  if (i < NE) atomicAdd(&deg[edst[i]], 1);
}

__global__ void dinv_kernel(const int* __restrict__ deg, float* __restrict__ dinv) {
  int v = blockIdx.x * 256 + threadIdx.x;
  if (v < NN) dinv[v] = rsqrtf((float)(deg[v] + 1));   // +1 self loop
}

// inclusive scan of counts (deg+1) in chunks of 1024
__global__ __launch_bounds__(1024) void scan1_kernel(const int* __restrict__ deg,
                                                     int* __restrict__ incl,
                                                     int* __restrict__ bsum) {
  __shared__ int sd[1024];
  int gid = blockIdx.x * 1024 + threadIdx.x;
  int v = (gid < NN) ? (deg[gid] + 1) : 0;
  sd[threadIdx.x] = v;
  __syncthreads();
  for (int off = 1; off < 1024; off <<= 1) {
    int t = (threadIdx.x >= off) ? sd[threadIdx.x - off] : 0;
    __syncthreads();
    sd[threadIdx.x] += t;
    __syncthreads();
  }
  if (gid < NN) incl[gid] = sd[threadIdx.x];
  if (threadIdx.x == 1023) bsum[blockIdx.x] = sd[1023];
}

__global__ void scan2_kernel(int* bsum, int nb) {
  if (threadIdx.x == 0 && blockIdx.x == 0) {
    int run = 0;
    for (int i = 0; i < nb; ++i) { int t = bsum[i]; bsum[i] = run; run += t; }
  }
}

__global__ void scan3_kernel(const int* __restrict__ deg, const int* __restrict__ incl,
                             const int* __restrict__ bsum, int* __restrict__ offs,
                             int* __restrict__ cursor) {
  int v = blockIdx.x * 256 + threadIdx.x;
  if (v >= NN) return;
  int o = bsum[v >> 10] + incl[v] - (deg[v] + 1);
  offs[v] = o;
  cursor[v] = o;
  if (v == 0) offs[NN] = NT;
}

__global__ void fill_kernel(const int* __restrict__ esrc, const int* __restrict__ edst,
                            const float* __restrict__ dinv, int* __restrict__ cursor,
                            int* __restrict__ csrc, float* __restrict__ cw) {
  int i = blockIdx.x * 256 + threadIdx.x;
  if (i >= NT) return;
  int s, d;
  if (i < NE) { s = esrc[i]; d = edst[i]; }
  else        { s = d = i - NE; }           // self loop
  int p = atomicAdd(&cursor[d], 1);
  csrc[p] = s;
  cw[p] = dinv[s] * dinv[d];
}

// ---------------- dense GEMM: out = A[M,K] @ W[K,COLS] + bias ----------------
// 512 threads (8 waves) per block; tile 64 rows x COLS; K-chunk 32.
// thread = (tid/16) row-pair x (tid%16) col-group of CPT; 2 x CPT outputs.
// LDS: xs stride 36 (144B rows: 16B-aligned float4 stores, 2-way-free banks),
// ws unpadded (float4 rows). ~25.6KB (COLS=128) -> 6 blocks/CU capacity.

template <int K, int COLS>
__global__ __launch_bounds__(512) void gemm_bias_kernel(const float* __restrict__ A,
                                                        const float* __restrict__ W,
                                                        const float* __restrict__ bias,
                                                        float* __restrict__ out, int M) {
  constexpr int CPT = COLS / 16;  // cols per thread (8 or 4)
  __shared__ float xs[64][36];
  __shared__ float ws[32][COLS];

  int tid = threadIdx.x;
  int tr = tid / 16;              // 0..31 row-pair group
  int tc = tid % 16;              // 0..15 col group
  int row0 = blockIdx.x * 64;

  float acc[2][CPT] = {};

  for (int kc = 0; kc < K; kc += 32) {
    // stage xs: 64 rows x 32 k = 512 float4, one per thread
    {
      int r = tid >> 3, k4 = tid & 7;
      int row = row0 + r;
      float4 v = make_float4(0.f, 0.f, 0.f, 0.f);
      if (row < M) v = *reinterpret_cast<const float4*>(&A[(size_t)row * K + kc + k4 * 4]);
      *reinterpret_cast<float4*>(&xs[r][k4 * 4]) = v;
    }
    // stage ws: 32 x COLS
    {
      constexpr int NV = 32 * COLS / 4;   // 1024 or 512 float4
      for (int i = tid; i < NV; i += 512) {
        int k = i / (COLS / 4), c4 = i % (COLS / 4);
        *reinterpret_cast<float4*>(&ws[k][c4 * 4]) =
            *reinterpret_cast<const float4*>(&W[(size_t)(kc + k) * COLS + c4 * 4]);
      }
    }
    __syncthreads();
#pragma unroll
    for (int k = 0; k < 32; ++k) {
      float xv0 = xs[tr * 2 + 0][k];
      float xv1 = xs[tr * 2 + 1][k];
      const float4* wrow = reinterpret_cast<const float4*>(&ws[k][tc * CPT]);
#pragma unroll
      for (int j4 = 0; j4 < CPT / 4; ++j4) {
        float4 wv = wrow[j4];
        acc[0][j4 * 4 + 0] += xv0 * wv.x;
        acc[0][j4 * 4 + 1] += xv0 * wv.y;
        acc[0][j4 * 4 + 2] += xv0 * wv.z;
        acc[0][j4 * 4 + 3] += xv0 * wv.w;
        acc[1][j4 * 4 + 0] += xv1 * wv.x;
        acc[1][j4 * 4 + 1] += xv1 * wv.y;
        acc[1][j4 * 4 + 2] += xv1 * wv.z;
        acc[1][j4 * 4 + 3] += xv1 * wv.w;
      }
    }
    __syncthreads();
  }

#pragma unroll
  for (int r = 0; r < 2; ++r) {
    int row = row0 + tr * 2 + r;
    if (row < M) {
#pragma unroll
      for (int j4 = 0; j4 < CPT / 4; ++j4) {
        int c = tc * CPT + j4 * 4;
        float4 o;
        o.x = acc[r][j4 * 4 + 0] + bias[c + 0];
        o.y = acc[r][j4 * 4 + 1] + bias[c + 1];
        o.z = acc[r][j4 * 4 + 2] + bias[c + 2];
        o.w = acc[r][j4 * 4 + 3] + bias[c + 3];
        *reinterpret_cast<float4*>(&out[(size_t)row * COLS + c]) = o;
      }
    }
  }
}

// ---------------- propagation: out[d] = (sum_e w_e * h[src_e])  [* 0.9 + 0.1 h0] ----
// F/4 threads per node, float4 gathers (16B/lane), 4-edge unroll -> 4 loads in flight.

template <int F, bool APPNP>
__global__ __launch_bounds__(256) void prop4_kernel(const float* __restrict__ hin,
                                                    const float* __restrict__ h0,
                                                    float* __restrict__ out,
                                                    const int* __restrict__ offs,
                                                    const int* __restrict__ csrc,
                                                    const float* __restrict__ cw) {
  constexpr int TPN = F / 4;        // threads per node (32 or 16)
  constexpr int NPB = 256 / TPN;    // nodes per block (8 or 16)
  int node = blockIdx.x * NPB + threadIdx.x / TPN;
  int f4 = threadIdx.x % TPN;
  if (node >= NN) return;
  int e = offs[node];
  int e1 = offs[node + 1];
  float ax = 0.f, ay = 0.f, az = 0.f, aw = 0.f;
  for (; e + 3 < e1; e += 4) {
    int s0 = csrc[e], s1 = csrc[e + 1], s2 = csrc[e + 2], s3 = csrc[e + 3];
    float w0 = cw[e], w1 = cw[e + 1], w2 = cw[e + 2], w3 = cw[e + 3];
    float4 v0 = *reinterpret_cast<const float4*>(&hin[(size_t)s0 * F + f4 * 4]);
    float4 v1 = *reinterpret_cast<const float4*>(&hin[(size_t)s1 * F + f4 * 4]);
    float4 v2 = *reinterpret_cast<const float4*>(&hin[(size_t)s2 * F + f4 * 4]);
    float4 v3 = *reinterpret_cast<const float4*>(&hin[(size_t)s3 * F + f4 * 4]);
    ax += w0 * v0.x + w1 * v1.x + w2 * v2.x + w3 * v3.x;
    ay += w0 * v0.y + w1 * v1.y + w2 * v2.y + w3 * v3.y;
    az += w0 * v0.z + w1 * v1.z + w2 * v2.z + w3 * v3.z;
    aw += w0 * v0.w + w1 * v1.w + w2 * v2.w + w3 * v3.w;
  }
  for (; e < e1; ++e) {
    int s = csrc[e];
    float wv = cw[e];
    float4 v = *reinterpret_cast<const float4*>(&hin[(size_t)s * F + f4 * 4]);
    ax += wv * v.x; ay += wv * v.y; az += wv * v.z; aw += wv * v.w;
  }
  if (APPNP) {
    float4 z = *reinterpret_cast<const float4*>(&h0[(size_t)node * F + f4 * 4]);
    ax = 0.9f * ax + 0.1f * z.x;
    ay = 0.9f * ay + 0.1f * z.y;
    az = 0.9f * az + 0.1f * z.z;
    aw = 0.9f * aw + 0.1f * z.w;
  }
  float4 o = make_float4(ax, ay, az, aw);
  *reinterpret_cast<float4*>(&out[(size_t)node * F + f4 * 4]) = o;
}

// ---------------- launch ----------------

extern "C" void kernel_launch(void* const* d_in, const int* in_sizes, int n_in,
                              void* d_out, int out_size, void* d_ws, size_t ws_size,
                              hipStream_t stream) {
  const float* x    = (const float*)d_in[0];   // [50000,256]
  const int*   eidx = (const int*)d_in[1];     // [2,800000]
  const float* W1   = (const float*)d_in[2];   // [256,128]
  const float* b1   = (const float*)d_in[3];   // [128]
  const float* W3   = (const float*)d_in[4];   // [128,64]
  const float* b3   = (const float*)d_in[5];   // [64]
  float* outp = (float*)d_out;                 // [50000,64]

  const int* esrc = eidx;
  const int* edst = eidx + NE;

  // workspace layout (256B aligned)
  char* w = (char*)d_ws;
  size_t off = 0;
  auto take = [&](size_t bytes) {
    void* p = w + off;
    off = (off + bytes + 255) & ~(size_t)255;
    return p;
  };
  int*   deg    = (int*)take(NN * 4);
  float* dinv   = (float*)take(NN * 4);
  int*   incl   = (int*)take(NN * 4);
  int*   offs   = (int*)take((NN + 1) * 4);
  int*   cursor = (int*)take(NN * 4);
  int*   bsum   = (int*)take(64 * 4);
  int*   csrc   = (int*)take((size_t)NT * 4);
  float* cwv    = (float*)take((size_t)NT * 4);
  float* h0b    = (float*)take((size_t)NN * 128 * 4);
  float* ping   = (float*)take((size_t)NN * 128 * 4);
  float* pong   = (float*)take((size_t)NN * 128 * 4);
  (void)ws_size; (void)in_sizes; (void)n_in; (void)out_size;

  const int nblkN = (NN + 255) / 256;          // 196
  const int nblkE = (NE + 255) / 256;          // 3125
  const int nblkT = (NT + 255) / 256;          // 3321
  const int nbScan = (NN + 1023) / 1024;       // 49

  // --- graph norm + CSR build ---
  zero_deg_kernel<<<nblkN, 256, 0, stream>>>(deg);
  count_deg_kernel<<<nblkE, 256, 0, stream>>>(edst, deg);
  dinv_kernel<<<nblkN, 256, 0, stream>>>(deg, dinv);
  scan1_kernel<<<nbScan, 1024, 0, stream>>>(deg, incl, bsum);
  scan2_kernel<<<1, 64, 0, stream>>>(bsum, nbScan);
  scan3_kernel<<<nblkN, 256, 0, stream>>>(deg, incl, bsum, offs, cursor);
  fill_kernel<<<nblkT, 256, 0, stream>>>(esrc, edst, dinv, cursor, csrc, cwv);

  // --- GCNConv1: h0 = prop(x @ W1 + b1) ---
  const int gblk = (NN + 63) / 64;             // 782
  gemm_bias_kernel<256, 128><<<gblk, 512, 0, stream>>>(x, W1, b1, ping, NN);
  prop4_kernel<128, false><<<(NN + 7) / 8, 256, 0, stream>>>(ping, nullptr, h0b, offs, csrc, cwv);

  // --- APPNP: 10 x h = 0.9*prop(h) + 0.1*h0 ---
  const float* hc = h0b;
  float* bufs[2] = {ping, pong};
  for (int it = 0; it < 10; ++it) {
    float* hn = bufs[it & 1];
    prop4_kernel<128, true><<<(NN + 7) / 8, 256, 0, stream>>>(hc, h0b, hn, offs, csrc, cwv);
    hc = hn;
  }
  // hc == pong after 10 iters; ping is free
  float* t64 = ping;

  // --- GCNConv2: out = prop(h @ W3 + b3) ---
  gemm_bias_kernel<128, 64><<<gblk, 512, 0, stream>>>(hc, W3, b3, t64, NN);
  prop4_kernel<64, false><<<(NN + 15) / 16, 256, 0, stream>>>(t64, nullptr, outp, offs, csrc, cwv);
}